// Round 13
// baseline (305.957 us; speedup 1.0000x reference)
//
#include <hip/hip_runtime.h>
#include <stdint.h>

#define S_LEN 2048
#define NB 32
#define NE 512
#define NU 512
#define NP 256
#define G1_BLOCKS 512

typedef __bf16 bf16;
typedef __bf16 bf16x8 __attribute__((ext_vector_type(8)));
typedef __bf16 bf16x4 __attribute__((ext_vector_type(4)));
typedef float f32x4 __attribute__((ext_vector_type(4)));
typedef float f32x8 __attribute__((ext_vector_type(8)));

__device__ __forceinline__ void gload16(const void* g, void* l) {
    __builtin_amdgcn_global_load_lds(
        (__attribute__((address_space(1))) void*)g,
        (__attribute__((address_space(3))) void*)l, 16, 0, 0);
}

// DPP helpers (HW-verified rounds 4-6)
__device__ __forceinline__ float dpp_shr1_z(float x) {
    return __builtin_bit_cast(float, __builtin_amdgcn_update_dpp(
        0, __builtin_bit_cast(int, x), 0x111, 0xF, 0xF, true));
}
__device__ __forceinline__ float dpp_shl1_z(float x) {
    return __builtin_bit_cast(float, __builtin_amdgcn_update_dpp(
        0, __builtin_bit_cast(int, x), 0x101, 0xF, 0xF, true));
}

// Stage a 128-row x 32-col bf16 tile (row stride SR) into 8KB LDS (256 thr);
// self-inverse k-quad permutation q = (c&3) ^ ((row>>1)&3).
__device__ __forceinline__ void stage_tile(const bf16* __restrict__ src, int SR,
                                           bf16* lds, int tid) {
#pragma unroll
    for (int rnd = 0; rnd < 2; ++rnd) {
        const int c = rnd * 256 + tid;
        const int row = c >> 2;
        const int q = (c & 3) ^ ((c >> 3) & 3);
        gload16(src + (size_t)row * SR + q * 8, lds + c * 8);
    }
}

// ---------------- kernel 0b: w1 fp32 -> bf16 hi/lo --------------------------
__global__ __launch_bounds__(256) void k_wconv(
    const float* __restrict__ w1, bf16* __restrict__ wHi, bf16* __restrict__ wLo)
{
    const int i = (blockIdx.x * 256 + threadIdx.x) * 4;
    const float4 v = *(const float4*)(w1 + i);
    const float vv[4] = {v.x, v.y, v.z, v.w};
    bf16x4 oh, ol;
#pragma unroll
    for (int q = 0; q < 4; ++q) {
        const bf16 hb = (bf16)vv[q];
        oh[q] = hb;
        ol[q] = (bf16)(vv[q] - (float)hb);
    }
    *(bf16x4*)(wHi + i) = oh;
    *(bf16x4*)(wLo + i) = ol;
}

// ---------------- kernel 1: GEMM1 (+fused prep transpose blocks) ------------
// Blocks [0,512): round-6 gemm1 (measured 159us), byte-identical inner loop.
// Blocks [512, 512+8192): prep transpose seq fp32 -> seqtH[b][e][s] bf16.
// prep depends only on seq, so it streams through CUs under gemm1's shadow
// (union LDS 32KB: 2 gemm1 + co-resident prep blocks per CU).
union G1Mem {
    struct { bf16 BhL[2][4096]; bf16 BlL[2][4096]; } gm;   // 32 KB
    float tile[64][65];                                     // 16.6 KB
};

__global__ __launch_bounds__(256, 2) void k_gemm1(
    const float* __restrict__ seq,
    const bf16* __restrict__ w1H, const bf16* __restrict__ w1L,
    const float* __restrict__ b1v, const float* __restrict__ w2,
    const float* __restrict__ b2v, float* __restrict__ actions,
    bf16* __restrict__ tHi)
{
    __shared__ __align__(16) G1Mem sm;
    const int tid = threadIdx.x;

    if (blockIdx.x >= G1_BLOCKS) {
        // ---- prep transpose path (identical math to previous k_scan_prep) --
        const int bid = blockIdx.x - G1_BLOCKS;
        const int b = bid >> 8;
        const int r = bid & 255;
        const int s0 = (r & 31) << 6;
        const int e0 = (r >> 5) << 6;
        const int tx = tid & 15, ty = tid >> 4;
        const float* src = seq + ((size_t)b * S_LEN + s0) * NE + e0;
#pragma unroll
        for (int i = 0; i < 4; ++i) {
            const int row = ty + i * 16;
            const float4 v = *(const float4*)(src + (size_t)row * NE + tx * 4);
            sm.tile[row][tx * 4 + 0] = v.x; sm.tile[row][tx * 4 + 1] = v.y;
            sm.tile[row][tx * 4 + 2] = v.z; sm.tile[row][tx * 4 + 3] = v.w;
        }
        __syncthreads();
        const int sx = tid & 7, ey = tid >> 3;
#pragma unroll
        for (int jj = 0; jj < 2; ++jj) {
            const int er = ey + jj * 32;
            bf16x8 oh;
#pragma unroll
            for (int q = 0; q < 8; ++q) oh[q] = (bf16)sm.tile[sx * 8 + q][er];
            *(bf16x8*)(tHi + ((size_t)b * NE + e0 + er) * S_LEN + s0 + sx * 8) = oh;
        }
        return;
    }

    // ---- gemm1 path (round-6 config, measured 159us) ----
    const int wid = tid >> 6;
    const int lane = tid & 63;
    const int lr = lane & 15, lg = lane >> 4;
    const int m0 = blockIdx.x << 7;

    const float* arow0 = seq + (size_t)(m0 + wid * 32 + lr) * NE + lg * 8;
    const float* arow1 = arow0 + 16 * NE;
    const int lroff = lr * 64 + (lg ^ ((lr >> 1) & 3)) * 16;

    float plog[3][2][4];
#pragma unroll
    for (int a = 0; a < 3; ++a)
#pragma unroll
        for (int i = 0; i < 2; ++i)
#pragma unroll
            for (int q = 0; q < 4; ++q) plog[a][i][q] = 0.f;

    f32x4 acc[2][8];
    stage_tile(w1H, NE, sm.gm.BhL[0], tid);
    stage_tile(w1L, NE, sm.gm.BlL[0], tid);
    f32x8 Aa0 = *(const f32x8*)(arow0);
    f32x8 Aa1 = *(const f32x8*)(arow1);
    f32x8 Ab0, Ab1;

#define G1_BODY(g, buf, Ac0, Ac1, An0, An1) do {                              \
        __syncthreads();                                                      \
        if (((g) & 15) == 0) {                                                \
            _Pragma("unroll") for (int i = 0; i < 2; ++i)                     \
            _Pragma("unroll") for (int j = 0; j < 8; ++j)                     \
                acc[i][j] = (f32x4)(0.f);                                     \
        }                                                                     \
        bf16x8 bh[8], bl[8];                                                  \
        _Pragma("unroll") for (int j = 0; j < 8; ++j) {                       \
            bh[j] = *(const bf16x8*)((const char*)sm.gm.BhL[buf] + j * 1024 + lroff);\
            bl[j] = *(const bf16x8*)((const char*)sm.gm.BlL[buf] + j * 1024 + lroff);\
        }                                                                     \
        __syncthreads();                                                      \
        if ((g) < 63) {                                                       \
            const int gn = (g) + 1;                                           \
            const int u0n = (gn >> 4) << 7;                                   \
            const int k0n = (gn & 15) << 5;                                   \
            An0 = *(const f32x8*)(arow0 + k0n);                               \
            An1 = *(const f32x8*)(arow1 + k0n);                               \
            stage_tile(w1H + (size_t)u0n * NE + k0n, NE, sm.gm.BhL[(buf) ^ 1], tid);\
            stage_tile(w1L + (size_t)u0n * NE + k0n, NE, sm.gm.BlL[(buf) ^ 1], tid);\
        }                                                                     \
        bf16x8 Ah0, Al0, Ah1, Al1;                                            \
        _Pragma("unroll") for (int q = 0; q < 8; ++q) {                       \
            const bf16 h0 = (bf16)Ac0[q];                                     \
            Ah0[q] = h0; Al0[q] = (bf16)(Ac0[q] - (float)h0);                 \
            const bf16 h1 = (bf16)Ac1[q];                                     \
            Ah1[q] = h1; Al1[q] = (bf16)(Ac1[q] - (float)h1);                 \
        }                                                                     \
        _Pragma("unroll") for (int j = 0; j < 8; ++j) {                       \
            acc[0][j] = __builtin_amdgcn_mfma_f32_16x16x32_bf16(Ah0, bh[j], acc[0][j], 0, 0, 0); \
            acc[0][j] = __builtin_amdgcn_mfma_f32_16x16x32_bf16(Ah0, bl[j], acc[0][j], 0, 0, 0); \
            acc[0][j] = __builtin_amdgcn_mfma_f32_16x16x32_bf16(Al0, bh[j], acc[0][j], 0, 0, 0); \
            acc[1][j] = __builtin_amdgcn_mfma_f32_16x16x32_bf16(Ah1, bh[j], acc[1][j], 0, 0, 0); \
            acc[1][j] = __builtin_amdgcn_mfma_f32_16x16x32_bf16(Ah1, bl[j], acc[1][j], 0, 0, 0); \
            acc[1][j] = __builtin_amdgcn_mfma_f32_16x16x32_bf16(Al1, bh[j], acc[1][j], 0, 0, 0); \
        }                                                                     \
        if (((g) & 15) == 15) {                                               \
            const int u0 = ((g) >> 4) << 7;                                   \
            _Pragma("unroll") for (int j = 0; j < 8; ++j) {                   \
                const int col = u0 + j * 16 + lr;                             \
                const float b1c = b1v[col];                                   \
                const float w20 = w2[col], w21 = w2[NU + col], w22 = w2[2 * NU + col]; \
                _Pragma("unroll") for (int i = 0; i < 2; ++i)                 \
                _Pragma("unroll") for (int q = 0; q < 4; ++q) {               \
                    const float x = acc[i][j][q] + b1c;                       \
                    const float hgate = x / (1.f + __expf(-x));               \
                    plog[0][i][q] = fmaf(hgate, w20, plog[0][i][q]);          \
                    plog[1][i][q] = fmaf(hgate, w21, plog[1][i][q]);          \
                    plog[2][i][q] = fmaf(hgate, w22, plog[2][i][q]);          \
                }                                                             \
            }                                                                 \
        }                                                                     \
    } while (0)

    for (int gg = 0; gg < 32; ++gg) {
        G1_BODY(2 * gg, 0, Aa0, Aa1, Ab0, Ab1);
        G1_BODY(2 * gg + 1, 1, Ab0, Ab1, Aa0, Aa1);
    }
#undef G1_BODY

#pragma unroll
    for (int m = 1; m < 16; m <<= 1) {
#pragma unroll
        for (int a = 0; a < 3; ++a)
#pragma unroll
            for (int i = 0; i < 2; ++i)
#pragma unroll
                for (int q = 0; q < 4; ++q)
                    plog[a][i][q] += __shfl_xor(plog[a][i][q], m);
    }
    const float bb0 = b2v[0], bb1 = b2v[1], bb2 = b2v[2];
    if (lr == 0) {
#pragma unroll
        for (int i = 0; i < 2; ++i)
#pragma unroll
            for (int q = 0; q < 4; ++q) {
                const int row = m0 + wid * 32 + i * 16 + lg * 4 + q;
                const float l0 = plog[0][i][q] + bb0;
                const float l1 = plog[1][i][q] + bb1;
                const float l2 = plog[2][i][q] + bb2;
                const float mx = fmaxf(l0, fmaxf(l1, l2));
                const float e0 = __expf(l0 - mx), e1 = __expf(l1 - mx), e2 = __expf(l2 - mx);
                const float inv = 1.f / (e0 + e1 + e2);
                *(float4*)(actions + (size_t)row * 4) = make_float4(e0 * inv, e1 * inv, e2 * inv, 0.f);
            }
    }
}

// ---------------- kernel 2: scan only (32 blocks, 5 waves) ------------------
struct ScanMem {
    float4 actbuf[3][256];      // 12 KB
    float  sums[2][256][16];    // 32 KB
};

__device__ __forceinline__ void rs_chunk(const float4* __restrict__ pb,
                                         float* __restrict__ so,
                                         float& rs, int lane)
{
    for (int w = 0; w < 32; ++w) {
        const int rtop = 255 - w * 8;
        const float4 e0 = pb[rtop],     e1 = pb[rtop - 1];
        const float4 e2 = pb[rtop - 2], e3 = pb[rtop - 3];
        const float4 e4 = pb[rtop - 4], e5 = pb[rtop - 5];
        const float4 e6 = pb[rtop - 6], e7 = pb[rtop - 7];
#define RS_STEP(E, k) do {                                                    \
        const float rsp = dpp_shr1_z(rs);                                     \
        const float s = (E).y * rsp;                                          \
        if (lane < 16) so[(rtop - (k)) * 16 + lane] = s;                      \
        rs = fmaf((E).x + (E).z, rs, s);                                      \
    } while (0)
        RS_STEP(e0, 0); RS_STEP(e1, 1); RS_STEP(e2, 2); RS_STEP(e3, 3);
        RS_STEP(e4, 4); RS_STEP(e5, 5); RS_STEP(e6, 6); RS_STEP(e7, 7);
#undef RS_STEP
    }
}

__device__ __forceinline__ void t_chunk(const float4* __restrict__ lb,
                                        const float* __restrict__ sp,
                                        float& T, bf16* __restrict__ obp,
                                        int tbase0, int w15)
{
    for (int w = 0; w < 32; ++w) {
        const int rtop = 255 - w * 8;
        const int tglob = tbase0 + rtop - 7;
        const float4 av0 = lb[rtop],     av1 = lb[rtop - 1];
        const float4 av2 = lb[rtop - 2], av3 = lb[rtop - 3];
        const float4 av4 = lb[rtop - 4], av5 = lb[rtop - 5];
        const float4 av6 = lb[rtop - 6], av7 = lb[rtop - 7];
        const float su0 = sp[rtop * 16],       su1 = sp[(rtop - 1) * 16];
        const float su2 = sp[(rtop - 2) * 16], su3 = sp[(rtop - 3) * 16];
        const float su4 = sp[(rtop - 4) * 16], su5 = sp[(rtop - 5) * 16];
        const float su6 = sp[(rtop - 6) * 16], su7 = sp[(rtop - 7) * 16];
        bf16x8 fr;
#define T_STEP(Av, Su, fi) do {                                               \
        const float a0 = (Av).x, a1 = (Av).y, a2 = (Av).z;                    \
        fr[fi] = (bf16)((a0 + a1) * T);                                       \
        const float nT = dpp_shl1_z(T);                                       \
        const float contrib = w15 ? (Su) : a0 * nT;                           \
        T = fmaf(a2, T, contrib);                                             \
    } while (0)
        T_STEP(av0, su0, 7); T_STEP(av1, su1, 6);
        T_STEP(av2, su2, 5); T_STEP(av3, su3, 4);
        T_STEP(av4, su4, 3); T_STEP(av5, su5, 2);
        T_STEP(av6, su6, 1); T_STEP(av7, su7, 0);
#undef T_STEP
        *(bf16x8*)(obp + tglob) = fr;
    }
}

__global__ __launch_bounds__(320) void k_scan(
    const float* __restrict__ actions, bf16* __restrict__ wsT)
{
    __shared__ ScanMem sm;
    const int tid = threadIdx.x;
    const int b = blockIdx.x;
    const int wid = tid >> 6;
    const int lane = tid & 63;
    const float4* actb = (const float4*)actions + (size_t)b * S_LEN;

    float rs = (lane == 0) ? 1.f : 0.f;
    float T = (wid == 0 && lane == 15) ? 1.f : 0.f;
    const int w15 = ((lane & 15) == 15) ? 1 : 0;
    bf16* obp = wsT + ((size_t)b * NP + wid * 64 + lane) * S_LEN;

    if (wid < 4) {
        gload16(actb + 1792 + wid * 64 + lane, &sm.actbuf[0][wid * 64]);
        gload16(actb + 1536 + wid * 64 + lane, &sm.actbuf[1][wid * 64]);
        asm volatile("s_waitcnt vmcnt(0)" ::: "memory");
    }
    __syncthreads();
    if (wid == 4) rs_chunk(sm.actbuf[0], &sm.sums[0][0][0], rs, lane);
    __syncthreads();

    int bufT = 0, bufP = 1, bufL = 2;
    for (int c = 0; c < 8; ++c) {
        if (wid < 4) {
            if (c < 6)
                gload16(actb + (1280 - c * 256) + wid * 64 + lane,
                        &sm.actbuf[bufL][wid * 64]);
            t_chunk(sm.actbuf[bufT],
                    &sm.sums[c & 1][0][wid * 4 + (lane >> 4)],
                    T, obp, 1792 - c * 256, w15);
            asm volatile("s_waitcnt vmcnt(0)" ::: "memory");
        } else {
            if (c < 7)
                rs_chunk(sm.actbuf[bufP], &sm.sums[(c + 1) & 1][0][0], rs, lane);
        }
        __syncthreads();
        const int t = bufT; bufT = bufP; bufP = bufL; bufL = t;
    }
}

// ---------------- kernel 3: GEMM2 partials (2-way k-split, LDS-staged) ------
__global__ __launch_bounds__(256, 2) void k_gemm2(
    const bf16* __restrict__ wsT, const bf16* __restrict__ seqtH,
    float* __restrict__ part)
{
    __shared__ __align__(16) bf16 AL[2][4096];
    __shared__ __align__(16) bf16 BL[2][4096];
    const int tid = threadIdx.x;
    const int wid = tid >> 6;
    const int lane = tid & 63;
    const int lr = lane & 15, lg = lane >> 4;
    const int bid = blockIdx.x;
    const int b = bid >> 4;
    const int sub = bid & 15;
    const int kc = sub >> 3;
    const int p0 = ((sub >> 2) & 1) << 7;
    const int e0 = (sub & 3) << 7;

    const bf16* Abase = wsT + ((size_t)b * NP + p0) * S_LEN + kc * 1024;
    const bf16* Bbase = seqtH + ((size_t)b * NE + e0) * S_LEN + kc * 1024;
    const int lroff = lr * 64 + (lg ^ ((lr >> 1) & 3)) * 16;

    f32x4 acc[2][8];
#pragma unroll
    for (int i = 0; i < 2; ++i)
#pragma unroll
        for (int j = 0; j < 8; ++j) acc[i][j] = (f32x4)(0.f);

    stage_tile(Abase, S_LEN, AL[0], tid);
    stage_tile(Bbase, S_LEN, BL[0], tid);

#define G2_BODY(kt, buf) do {                                                 \
        __syncthreads();                                                      \
        bf16x8 af[2], bfv[8];                                                 \
        _Pragma("unroll") for (int i = 0; i < 2; ++i)                         \
            af[i] = *(const bf16x8*)((const char*)AL[buf]                     \
                     + (wid * 32 + i * 16) * 64 + lroff);                     \
        _Pragma("unroll") for (int j = 0; j < 8; ++j)                         \
            bfv[j] = *(const bf16x8*)((const char*)BL[buf] + j * 1024 + lroff);\
        __syncthreads();                                                      \
        if ((kt) < 31) {                                                      \
            stage_tile(Abase + ((kt) + 1) * 32, S_LEN, AL[(buf) ^ 1], tid);   \
            stage_tile(Bbase + ((kt) + 1) * 32, S_LEN, BL[(buf) ^ 1], tid);   \
        }                                                                     \
        _Pragma("unroll") for (int j = 0; j < 8; ++j) {                       \
            acc[0][j] = __builtin_amdgcn_mfma_f32_16x16x32_bf16(af[0], bfv[j], acc[0][j], 0, 0, 0); \
            acc[1][j] = __builtin_amdgcn_mfma_f32_16x16x32_bf16(af[1], bfv[j], acc[1][j], 0, 0, 0); \
        }                                                                     \
    } while (0)

    for (int kk = 0; kk < 16; ++kk) {
        G2_BODY(2 * kk, 0);
        G2_BODY(2 * kk + 1, 1);
    }
#undef G2_BODY

    float* obp = part + (((size_t)kc * NB + b) * NP + p0 + wid * 32) * NE + e0;
#pragma unroll
    for (int i = 0; i < 2; ++i)
#pragma unroll
        for (int j = 0; j < 8; ++j)
#pragma unroll
            for (int q = 0; q < 4; ++q)
                obp[(size_t)(i * 16 + lg * 4 + q) * NE + j * 16 + lr] = acc[i][j][q];
}

// ---------------- kernel 4: reduce the 2 partials ---------------------------
__global__ __launch_bounds__(256) void k_gred(
    const float* __restrict__ part, float* __restrict__ outp)
{
    const size_t i = ((size_t)blockIdx.x * 256 + threadIdx.x) * 4;
    const float4 p0 = *(const float4*)(part + i);
    const float4 p1 = *(const float4*)(part + ((size_t)NB * NP * NE) + i);
    *(float4*)(outp + i) = make_float4(p0.x + p1.x, p0.y + p1.y,
                                       p0.z + p1.z, p0.w + p1.w);
}

// ---------------- launch ----------------------------------------------------
extern "C" void kernel_launch(void* const* d_in, const int* in_sizes, int n_in,
                              void* d_out, int out_size, void* d_ws, size_t ws_size,
                              hipStream_t stream) {
    (void)in_sizes; (void)n_in; (void)out_size; (void)ws_size;
    const float* seq = (const float*)d_in[0];
    const float* w1  = (const float*)d_in[1];
    const float* b1  = (const float*)d_in[2];
    const float* w2  = (const float*)d_in[3];
    const float* b2  = (const float*)d_in[4];
    float* outp = (float*)d_out;

    char* ws = (char*)d_ws;
    bf16*  seqtH   = (bf16*)(ws);                        // 64 MB [b][e][s]
    bf16*  wsT     = (bf16*)(ws + (64ull << 20));        // 32 MB [b][p][t]
    float* actions = (float*)(ws + (96ull << 20));       // 1 MB  [b*S][4]
    bf16*  w1H     = (bf16*)(ws + (97ull << 20));        // 512 KB
    bf16*  w1L     = (bf16*)(ws + (97ull << 20) + (512u << 10)); // 512 KB
    float* part    = (float*)(ws + (98ull << 20));       // 32 MB [2][b][p][e]

    hipLaunchKernelGGL(k_wconv, dim3(256), dim3(256), 0, stream, w1, w1H, w1L);
    hipLaunchKernelGGL(k_gemm1, dim3(G1_BLOCKS + 8192), dim3(256), 0, stream,
                       seq, w1H, w1L, b1, w2, b2, actions, seqtH);
    hipLaunchKernelGGL(k_scan,  dim3(32),   dim3(320), 0, stream, actions, wsT);
    hipLaunchKernelGGL(k_gemm2, dim3(512),  dim3(256), 0, stream, wsT, seqtH, part);
    hipLaunchKernelGGL(k_gred,  dim3(4096), dim3(256), 0, stream, part, outp);
}

// Round 14
// 284.834 us; speedup vs baseline: 1.0742x; 1.0742x over previous
//
#include <hip/hip_runtime.h>
#include <stdint.h>

#define S_LEN 2048
#define NB 32
#define NE 512
#define NU 512
#define NP 256
#define SCAN_BLOCKS 128

typedef __bf16 bf16;
typedef __bf16 bf16x8 __attribute__((ext_vector_type(8)));
typedef __bf16 bf16x4 __attribute__((ext_vector_type(4)));
typedef float f32x4 __attribute__((ext_vector_type(4)));
typedef float f32x8 __attribute__((ext_vector_type(8)));

__device__ __forceinline__ void gload16(const void* g, void* l) {
    __builtin_amdgcn_global_load_lds(
        (__attribute__((address_space(1))) void*)g,
        (__attribute__((address_space(3))) void*)l, 16, 0, 0);
}

// DPP helpers (HW-verified rounds 4-6)
__device__ __forceinline__ float dpp_shr1_z(float x) {
    return __builtin_bit_cast(float, __builtin_amdgcn_update_dpp(
        0, __builtin_bit_cast(int, x), 0x111, 0xF, 0xF, true));
}
__device__ __forceinline__ float dpp_shl1_z(float x) {
    return __builtin_bit_cast(float, __builtin_amdgcn_update_dpp(
        0, __builtin_bit_cast(int, x), 0x101, 0xF, 0xF, true));
}

// Stage a 128-row x 32-col bf16 tile (row stride SR) into 8KB LDS (256 thr);
// self-inverse k-quad permutation q = (c&3) ^ ((row>>1)&3).
__device__ __forceinline__ void stage_tile(const bf16* __restrict__ src, int SR,
                                           bf16* lds, int tid) {
#pragma unroll
    for (int rnd = 0; rnd < 2; ++rnd) {
        const int c = rnd * 256 + tid;
        const int row = c >> 2;
        const int q = (c & 3) ^ ((c >> 3) & 3);
        gload16(src + (size_t)row * SR + q * 8, lds + c * 8);
    }
}

// ---------------- kernel 0b: w1 fp32 -> bf16 hi/lo --------------------------
__global__ __launch_bounds__(256) void k_wconv(
    const float* __restrict__ w1, bf16* __restrict__ wHi, bf16* __restrict__ wLo)
{
    const int i = (blockIdx.x * 256 + threadIdx.x) * 4;
    const float4 v = *(const float4*)(w1 + i);
    const float vv[4] = {v.x, v.y, v.z, v.w};
    bf16x4 oh, ol;
#pragma unroll
    for (int q = 0; q < 4; ++q) {
        const bf16 hb = (bf16)vv[q];
        oh[q] = hb;
        ol[q] = (bf16)(vv[q] - (float)hb);
    }
    *(bf16x4*)(wHi + i) = oh;
    *(bf16x4*)(wLo + i) = ol;
}

// ---------------- kernel 1: GEMM1 + silu + logits + softmax -----------------
// Round-11 version exactly (measured 158.9us).
__global__ __launch_bounds__(256, 2) void k_gemm1(
    const float* __restrict__ seq,
    const bf16* __restrict__ w1H, const bf16* __restrict__ w1L,
    const float* __restrict__ b1v, const float* __restrict__ w2,
    const float* __restrict__ b2v, float* __restrict__ actions)
{
    __shared__ __align__(16) bf16 BhL[2][4096];
    __shared__ __align__(16) bf16 BlL[2][4096];
    const int tid = threadIdx.x;
    const int wid = tid >> 6;
    const int lane = tid & 63;
    const int lr = lane & 15, lg = lane >> 4;
    const int m0 = blockIdx.x << 7;

    const float* arow0 = seq + (size_t)(m0 + wid * 32 + lr) * NE + lg * 8;
    const float* arow1 = arow0 + 16 * NE;
    const int lroff = lr * 64 + (lg ^ ((lr >> 1) & 3)) * 16;

    float plog[3][2][4];
#pragma unroll
    for (int a = 0; a < 3; ++a)
#pragma unroll
        for (int i = 0; i < 2; ++i)
#pragma unroll
            for (int q = 0; q < 4; ++q) plog[a][i][q] = 0.f;

    f32x4 acc[2][8];
    stage_tile(w1H, NE, BhL[0], tid);
    stage_tile(w1L, NE, BlL[0], tid);
    f32x8 Aa0 = *(const f32x8*)(arow0);
    f32x8 Aa1 = *(const f32x8*)(arow1);
    f32x8 Ab0, Ab1;

#define G1_BODY(g, buf, Ac0, Ac1, An0, An1) do {                              \
        __syncthreads();                                                      \
        if (((g) & 15) == 0) {                                                \
            _Pragma("unroll") for (int i = 0; i < 2; ++i)                     \
            _Pragma("unroll") for (int j = 0; j < 8; ++j)                     \
                acc[i][j] = (f32x4)(0.f);                                     \
        }                                                                     \
        bf16x8 bh[8], bl[8];                                                  \
        _Pragma("unroll") for (int j = 0; j < 8; ++j) {                       \
            bh[j] = *(const bf16x8*)((const char*)BhL[buf] + j * 1024 + lroff);\
            bl[j] = *(const bf16x8*)((const char*)BlL[buf] + j * 1024 + lroff);\
        }                                                                     \
        __syncthreads();                                                      \
        if ((g) < 63) {                                                       \
            const int gn = (g) + 1;                                           \
            const int u0n = (gn >> 4) << 7;                                   \
            const int k0n = (gn & 15) << 5;                                   \
            An0 = *(const f32x8*)(arow0 + k0n);                               \
            An1 = *(const f32x8*)(arow1 + k0n);                               \
            stage_tile(w1H + (size_t)u0n * NE + k0n, NE, BhL[(buf) ^ 1], tid);\
            stage_tile(w1L + (size_t)u0n * NE + k0n, NE, BlL[(buf) ^ 1], tid);\
        }                                                                     \
        bf16x8 Ah0, Al0, Ah1, Al1;                                            \
        _Pragma("unroll") for (int q = 0; q < 8; ++q) {                       \
            const bf16 h0 = (bf16)Ac0[q];                                     \
            Ah0[q] = h0; Al0[q] = (bf16)(Ac0[q] - (float)h0);                 \
            const bf16 h1 = (bf16)Ac1[q];                                     \
            Ah1[q] = h1; Al1[q] = (bf16)(Ac1[q] - (float)h1);                 \
        }                                                                     \
        _Pragma("unroll") for (int j = 0; j < 8; ++j) {                       \
            acc[0][j] = __builtin_amdgcn_mfma_f32_16x16x32_bf16(Ah0, bh[j], acc[0][j], 0, 0, 0); \
            acc[0][j] = __builtin_amdgcn_mfma_f32_16x16x32_bf16(Ah0, bl[j], acc[0][j], 0, 0, 0); \
            acc[0][j] = __builtin_amdgcn_mfma_f32_16x16x32_bf16(Al0, bh[j], acc[0][j], 0, 0, 0); \
            acc[1][j] = __builtin_amdgcn_mfma_f32_16x16x32_bf16(Ah1, bh[j], acc[1][j], 0, 0, 0); \
            acc[1][j] = __builtin_amdgcn_mfma_f32_16x16x32_bf16(Ah1, bl[j], acc[1][j], 0, 0, 0); \
            acc[1][j] = __builtin_amdgcn_mfma_f32_16x16x32_bf16(Al1, bh[j], acc[1][j], 0, 0, 0); \
        }                                                                     \
        if (((g) & 15) == 15) {                                               \
            const int u0 = ((g) >> 4) << 7;                                   \
            _Pragma("unroll") for (int j = 0; j < 8; ++j) {                   \
                const int col = u0 + j * 16 + lr;                             \
                const float b1c = b1v[col];                                   \
                const float w20 = w2[col], w21 = w2[NU + col], w22 = w2[2 * NU + col]; \
                _Pragma("unroll") for (int i = 0; i < 2; ++i)                 \
                _Pragma("unroll") for (int q = 0; q < 4; ++q) {               \
                    const float x = acc[i][j][q] + b1c;                       \
                    const float hgate = x / (1.f + __expf(-x));               \
                    plog[0][i][q] = fmaf(hgate, w20, plog[0][i][q]);          \
                    plog[1][i][q] = fmaf(hgate, w21, plog[1][i][q]);          \
                    plog[2][i][q] = fmaf(hgate, w22, plog[2][i][q]);          \
                }                                                             \
            }                                                                 \
        }                                                                     \
    } while (0)

    for (int gg = 0; gg < 32; ++gg) {
        G1_BODY(2 * gg, 0, Aa0, Aa1, Ab0, Ab1);
        G1_BODY(2 * gg + 1, 1, Ab0, Ab1, Aa0, Aa1);
    }
#undef G1_BODY

#pragma unroll
    for (int m = 1; m < 16; m <<= 1) {
#pragma unroll
        for (int a = 0; a < 3; ++a)
#pragma unroll
            for (int i = 0; i < 2; ++i)
#pragma unroll
                for (int q = 0; q < 4; ++q)
                    plog[a][i][q] += __shfl_xor(plog[a][i][q], m);
    }
    const float bb0 = b2v[0], bb1 = b2v[1], bb2 = b2v[2];
    if (lr == 0) {
#pragma unroll
        for (int i = 0; i < 2; ++i)
#pragma unroll
            for (int q = 0; q < 4; ++q) {
                const int row = m0 + wid * 32 + i * 16 + lg * 4 + q;
                const float l0 = plog[0][i][q] + bb0;
                const float l1 = plog[1][i][q] + bb1;
                const float l2 = plog[2][i][q] + bb2;
                const float mx = fmaxf(l0, fmaxf(l1, l2));
                const float e0 = __expf(l0 - mx), e1 = __expf(l1 - mx), e2 = __expf(l2 - mx);
                const float inv = 1.f / (e0 + e1 + e2);
                *(float4*)(actions + (size_t)row * 4) = make_float4(e0 * inv, e1 * inv, e2 * inv, 0.f);
            }
    }
}

// ---------------- fused kernel: h-split scan (blocks 0..127) + prep ---------
// 4 scan blocks per batch, each on its own CU: wave0 = T consumer for 4
// h-rows (hb*4..hb*4+4), wave1 = rs producer (full 16-h recurrence,
// duplicated per block; stores sums only for this block's h-range),
// waves 2-3 idle (barriers + staging only). Cuts per-CU LDS-pipe pressure
// ~4x vs the single-block-per-batch layout. Math bit-identical.
union SPMem {
    float tile[64][65];                    // prep path (16.6 KB)
    struct {
        float4 actbuf[3][256];             // 12 KB
        float  sums[2][256][4];            // 8 KB
    } s;
};

__device__ __forceinline__ void rs_chunk4(const float4* __restrict__ pb,
                                          float* __restrict__ so,
                                          float& rs, int lane, int hb)
{
    const int hl = lane - hb * 4;
    const bool st = (lane >= hb * 4) && (lane < hb * 4 + 4);
    for (int w = 0; w < 32; ++w) {
        const int rtop = 255 - w * 8;
        const float4 e0 = pb[rtop],     e1 = pb[rtop - 1];
        const float4 e2 = pb[rtop - 2], e3 = pb[rtop - 3];
        const float4 e4 = pb[rtop - 4], e5 = pb[rtop - 5];
        const float4 e6 = pb[rtop - 6], e7 = pb[rtop - 7];
#define RS_STEP(E, k) do {                                                    \
        const float rsp = dpp_shr1_z(rs);                                     \
        const float s = (E).y * rsp;                                          \
        if (st) so[(rtop - (k)) * 4 + hl] = s;                                \
        rs = fmaf((E).x + (E).z, rs, s);                                      \
    } while (0)
        RS_STEP(e0, 0); RS_STEP(e1, 1); RS_STEP(e2, 2); RS_STEP(e3, 3);
        RS_STEP(e4, 4); RS_STEP(e5, 5); RS_STEP(e6, 6); RS_STEP(e7, 7);
#undef RS_STEP
    }
}

__device__ __forceinline__ void t_chunk4(const float4* __restrict__ lb,
                                         const float* __restrict__ sp,
                                         float& T, bf16* __restrict__ obp,
                                         int tbase0, int w15)
{
    for (int w = 0; w < 32; ++w) {
        const int rtop = 255 - w * 8;
        const int tglob = tbase0 + rtop - 7;
        const float4 av0 = lb[rtop],     av1 = lb[rtop - 1];
        const float4 av2 = lb[rtop - 2], av3 = lb[rtop - 3];
        const float4 av4 = lb[rtop - 4], av5 = lb[rtop - 5];
        const float4 av6 = lb[rtop - 6], av7 = lb[rtop - 7];
        const float su0 = sp[rtop * 4],       su1 = sp[(rtop - 1) * 4];
        const float su2 = sp[(rtop - 2) * 4], su3 = sp[(rtop - 3) * 4];
        const float su4 = sp[(rtop - 4) * 4], su5 = sp[(rtop - 5) * 4];
        const float su6 = sp[(rtop - 6) * 4], su7 = sp[(rtop - 7) * 4];
        bf16x8 fr;
#define T_STEP(Av, Su, fi) do {                                               \
        const float a0 = (Av).x, a1 = (Av).y, a2 = (Av).z;                    \
        fr[fi] = (bf16)((a0 + a1) * T);                                       \
        const float nT = dpp_shl1_z(T);                                       \
        const float contrib = w15 ? (Su) : a0 * nT;                           \
        T = fmaf(a2, T, contrib);                                             \
    } while (0)
        T_STEP(av0, su0, 7); T_STEP(av1, su1, 6);
        T_STEP(av2, su2, 5); T_STEP(av3, su3, 4);
        T_STEP(av4, su4, 3); T_STEP(av5, su5, 2);
        T_STEP(av6, su6, 1); T_STEP(av7, su7, 0);
#undef T_STEP
        *(bf16x8*)(obp + tglob) = fr;
    }
}

__global__ __launch_bounds__(256) void k_scan_prep(
    const float* __restrict__ actions, bf16* __restrict__ wsT,
    const float* __restrict__ seq, bf16* __restrict__ tHi)
{
    __shared__ SPMem sm;
    const int tid = threadIdx.x;
    if (blockIdx.x < SCAN_BLOCKS) {
        const int b = blockIdx.x >> 2;
        const int hb = blockIdx.x & 3;
        const int wid = tid >> 6;
        const int lane = tid & 63;
        const float4* actb = (const float4*)actions + (size_t)b * S_LEN;

        float rs = (lane == 0) ? 1.f : 0.f;                           // wave1 state
        float T = (hb == 0 && wid == 0 && lane == 15) ? 1.f : 0.f;    // (h=0,w=15)
        const int w15 = ((lane & 15) == 15) ? 1 : 0;
        bf16* obp = wsT + ((size_t)b * NP + hb * 64 + lane) * S_LEN;

        // prologue: stage chunks 0,1 (all 256 threads, one float4 each)
        gload16(actb + 1792 + tid, &sm.s.actbuf[0][tid]);
        gload16(actb + 1536 + tid, &sm.s.actbuf[1][tid]);
        asm volatile("s_waitcnt vmcnt(0)" ::: "memory");
        __syncthreads();
        if (wid == 1) rs_chunk4(sm.s.actbuf[0], &sm.s.sums[0][0][0], rs, lane, hb);
        __syncthreads();

        int bufT = 0, bufP = 1, bufL = 2;
        for (int c = 0; c < 8; ++c) {
            if (c < 6)
                gload16(actb + (1280 - c * 256) + tid, &sm.s.actbuf[bufL][tid]);
            if (wid == 0)
                t_chunk4(sm.s.actbuf[bufT], &sm.s.sums[c & 1][0][lane >> 4],
                         T, obp, 1792 - c * 256, w15);
            else if (wid == 1 && c < 7)
                rs_chunk4(sm.s.actbuf[bufP], &sm.s.sums[(c + 1) & 1][0][0], rs, lane, hb);
            asm volatile("s_waitcnt vmcnt(0)" ::: "memory");
            __syncthreads();
            const int t = bufT; bufT = bufP; bufP = bufL; bufL = t;
        }
        return;
    }
    // ---- prep transpose path (seq fp32 -> seqtH[b][e][s] bf16) ----
    const int bid = blockIdx.x - SCAN_BLOCKS;
    const int b = bid >> 8;
    const int r = bid & 255;
    const int s0 = (r & 31) << 6;
    const int e0 = (r >> 5) << 6;
    const int tx = tid & 15, ty = tid >> 4;
    const float* src = seq + ((size_t)b * S_LEN + s0) * NE + e0;
#pragma unroll
    for (int i = 0; i < 4; ++i) {
        const int row = ty + i * 16;
        const float4 v = *(const float4*)(src + (size_t)row * NE + tx * 4);
        sm.tile[row][tx * 4 + 0] = v.x; sm.tile[row][tx * 4 + 1] = v.y;
        sm.tile[row][tx * 4 + 2] = v.z; sm.tile[row][tx * 4 + 3] = v.w;
    }
    __syncthreads();
    const int sx = tid & 7, ey = tid >> 3;
#pragma unroll
    for (int jj = 0; jj < 2; ++jj) {
        const int er = ey + jj * 32;
        bf16x8 oh;
#pragma unroll
        for (int q = 0; q < 8; ++q) oh[q] = (bf16)sm.tile[sx * 8 + q][er];
        *(bf16x8*)(tHi + ((size_t)b * NE + e0 + er) * S_LEN + s0 + sx * 8) = oh;
    }
}

// ---------------- kernel 3: GEMM2 partials (2-way k-split, LDS-staged) ------
__global__ __launch_bounds__(256, 2) void k_gemm2(
    const bf16* __restrict__ wsT, const bf16* __restrict__ seqtH,
    float* __restrict__ part)
{
    __shared__ __align__(16) bf16 AL[2][4096];
    __shared__ __align__(16) bf16 BL[2][4096];
    const int tid = threadIdx.x;
    const int wid = tid >> 6;
    const int lane = tid & 63;
    const int lr = lane & 15, lg = lane >> 4;
    const int bid = blockIdx.x;
    const int b = bid >> 4;
    const int sub = bid & 15;
    const int kc = sub >> 3;
    const int p0 = ((sub >> 2) & 1) << 7;
    const int e0 = (sub & 3) << 7;

    const bf16* Abase = wsT + ((size_t)b * NP + p0) * S_LEN + kc * 1024;
    const bf16* Bbase = seqtH + ((size_t)b * NE + e0) * S_LEN + kc * 1024;
    const int lroff = lr * 64 + (lg ^ ((lr >> 1) & 3)) * 16;

    f32x4 acc[2][8];
#pragma unroll
    for (int i = 0; i < 2; ++i)
#pragma unroll
        for (int j = 0; j < 8; ++j) acc[i][j] = (f32x4)(0.f);

    stage_tile(Abase, S_LEN, AL[0], tid);
    stage_tile(Bbase, S_LEN, BL[0], tid);

#define G2_BODY(kt, buf) do {                                                 \
        __syncthreads();                                                      \
        bf16x8 af[2], bfv[8];                                                 \
        _Pragma("unroll") for (int i = 0; i < 2; ++i)                         \
            af[i] = *(const bf16x8*)((const char*)AL[buf]                     \
                     + (wid * 32 + i * 16) * 64 + lroff);                     \
        _Pragma("unroll") for (int j = 0; j < 8; ++j)                         \
            bfv[j] = *(const bf16x8*)((const char*)BL[buf] + j * 1024 + lroff);\
        __syncthreads();                                                      \
        if ((kt) < 31) {                                                      \
            stage_tile(Abase + ((kt) + 1) * 32, S_LEN, AL[(buf) ^ 1], tid);   \
            stage_tile(Bbase + ((kt) + 1) * 32, S_LEN, BL[(buf) ^ 1], tid);   \
        }                                                                     \
        _Pragma("unroll") for (int j = 0; j < 8; ++j) {                       \
            acc[0][j] = __builtin_amdgcn_mfma_f32_16x16x32_bf16(af[0], bfv[j], acc[0][j], 0, 0, 0); \
            acc[1][j] = __builtin_amdgcn_mfma_f32_16x16x32_bf16(af[1], bfv[j], acc[1][j], 0, 0, 0); \
        }                                                                     \
    } while (0)

    for (int kk = 0; kk < 16; ++kk) {
        G2_BODY(2 * kk, 0);
        G2_BODY(2 * kk + 1, 1);
    }
#undef G2_BODY

    float* obp = part + (((size_t)kc * NB + b) * NP + p0 + wid * 32) * NE + e0;
#pragma unroll
    for (int i = 0; i < 2; ++i)
#pragma unroll
        for (int j = 0; j < 8; ++j)
#pragma unroll
            for (int q = 0; q < 4; ++q)
                obp[(size_t)(i * 16 + lg * 4 + q) * NE + j * 16 + lr] = acc[i][j][q];
}

// ---------------- kernel 4: reduce the 2 partials ---------------------------
__global__ __launch_bounds__(256) void k_gred(
    const float* __restrict__ part, float* __restrict__ outp)
{
    const size_t i = ((size_t)blockIdx.x * 256 + threadIdx.x) * 4;
    const float4 p0 = *(const float4*)(part + i);
    const float4 p1 = *(const float4*)(part + ((size_t)NB * NP * NE) + i);
    *(float4*)(outp + i) = make_float4(p0.x + p1.x, p0.y + p1.y,
                                       p0.z + p1.z, p0.w + p1.w);
}

// ---------------- launch ----------------------------------------------------
extern "C" void kernel_launch(void* const* d_in, const int* in_sizes, int n_in,
                              void* d_out, int out_size, void* d_ws, size_t ws_size,
                              hipStream_t stream) {
    (void)in_sizes; (void)n_in; (void)out_size; (void)ws_size;
    const float* seq = (const float*)d_in[0];
    const float* w1  = (const float*)d_in[1];
    const float* b1  = (const float*)d_in[2];
    const float* w2  = (const float*)d_in[3];
    const float* b2  = (const float*)d_in[4];
    float* outp = (float*)d_out;

    char* ws = (char*)d_ws;
    bf16*  seqtH   = (bf16*)(ws);                        // 64 MB [b][e][s]
    bf16*  wsT     = (bf16*)(ws + (64ull << 20));        // 32 MB [b][p][t]
    float* actions = (float*)(ws + (96ull << 20));       // 1 MB  [b*S][4]
    bf16*  w1H     = (bf16*)(ws + (97ull << 20));        // 512 KB
    bf16*  w1L     = (bf16*)(ws + (97ull << 20) + (512u << 10)); // 512 KB
    float* part    = (float*)(ws + (98ull << 20));       // 32 MB [2][b][p][e]

    hipLaunchKernelGGL(k_wconv, dim3(256), dim3(256), 0, stream, w1, w1H, w1L);
    hipLaunchKernelGGL(k_gemm1, dim3(512), dim3(256), 0, stream,
                       seq, w1H, w1L, b1, w2, b2, actions);
    hipLaunchKernelGGL(k_scan_prep, dim3(SCAN_BLOCKS + 8192), dim3(256), 0, stream,
                       actions, wsT, seq, seqtH);
    hipLaunchKernelGGL(k_gemm2, dim3(512),  dim3(256), 0, stream, wsT, seqtH, part);
    hipLaunchKernelGGL(k_gred,  dim3(4096), dim3(256), 0, stream, part, outp);
}